// Round 4
// baseline (243.286 us; speedup 1.0000x reference)
//
#include <hip/hip_runtime.h>
#include <math.h>

// x [B=256, T=4096, C=32] f32 -> out [B, 64, 64, 32] f32, PAA=64, GADF.
//
// R6: DISCRIMINATING EXPERIMENT round.
//  - K1 gaf_stats now uses NON-TEMPORAL loads (nt flag; bypass L2 read-allocate:
//    134 MB streaming through 32 MB L2 forces allocate+evict per line otherwise).
//  - K1 is launched TWICE (idempotent: pure function x->ws). With the calibrated
//    ~149 us fixed overhead, dur_us = 149 + 2*K1 + K2 reveals K1's absolute time,
//    which has never been directly observable (both split kernels < 80 us fills).
//    Readout: ~225 => NT fixed reads; ~300 => reads hard-capped ~2.2 TB/s;
//             ~260 => K2 is the slow kernel (or NT partial).
//  - K2 unchanged from R3 (plain stores; NT stores already shown null in R2).

#define BB   256
#define TT   4096
#define CC   32
#define PP   64
#define PSTR 33

typedef float f32x4 __attribute__((ext_vector_type(4)));

// ws layout (floats)
#define SUM_OFF    0                        // [b][64][32] raw segment sums (2 MB)
#define SUM_FLOATS (BB * PP * CC)           // 524288
#define MN_OFF     SUM_FLOATS               // [b][16][32] block-level mins (512 KB)
#define MM_FLOATS  (BB * 16 * CC)           // 131072
#define MX_OFF     (MN_OFF + MM_FLOATS)     // [b][16][32] block-level maxs
#define WS_FLOATS  (MX_OFF + MM_FLOATS)     // 786432 floats = 3 MB
#define WS_BYTES   (WS_FLOATS * 4)

__device__ __forceinline__ float4 f4min(float4 a, float4 b) {
    return make_float4(fminf(a.x,b.x), fminf(a.y,b.y), fminf(a.z,b.z), fminf(a.w,b.w));
}
__device__ __forceinline__ float4 f4max(float4 a, float4 b) {
    return make_float4(fmaxf(a.x,b.x), fmaxf(a.y,b.y), fmaxf(a.z,b.z), fmaxf(a.w,b.w));
}
__device__ __forceinline__ void f4add(float4& a, float4 v) {
    a.x += v.x; a.y += v.y; a.z += v.z; a.w += v.w;
}
__device__ __forceinline__ float4 shflxor4(float4 v, int m) {
    return make_float4(__shfl_xor(v.x, m), __shfl_xor(v.y, m),
                       __shfl_xor(v.z, m), __shfl_xor(v.w, m));
}
__device__ __forceinline__ float4 ntload4(const float4* src) {
    f32x4 t = __builtin_nontemporal_load((const f32x4*)src);
    return make_float4(t.x, t.y, t.z, t.w);
}

// ---------------- K1: dense-window streaming stats (NT loads) ----------------
// Wave W = blk*4+wave. Step u: f4 addr = u*2M + W*512 + v*64 + lane, v=0..7.
// Decode: b = u*64 + (W>>6); s = W&63 (full segment owned in-wave).
__global__ __launch_bounds__(256, 4) void gaf_stats(const float* __restrict__ x,
                                                    float* __restrict__ ws) {
    __shared__ float4 cmn[4][4][8];   // [wave][step][cg]
    __shared__ float4 cmx[4][4][8];

    const int tid  = threadIdx.x;
    const int lane = tid & 63;
    const int wave = tid >> 6;        // 0..3
    const int cg   = lane & 7;
    const int blk  = blockIdx.x;
    const int W    = blk * 4 + wave;  // 0..4095
    const int s    = W & 63;          // segment owned by this wave
    const int bofs = W >> 6;          // b = u*64 + bofs (uniform across block)

    const float4* xb = (const float4*)x + (size_t)W * 512 + lane;

    float4 mnS[4], mxS[4];

    #pragma unroll
    for (int u = 0; u < 4; ++u) {
        const float4* g = xb + (size_t)u * 2097152;   // 32 MB window step
        float4 buf[8];
        #pragma unroll
        for (int v = 0; v < 8; ++v) buf[v] = ntload4(&g[v * 64]);

        float4 mn = buf[0], mx = buf[0], acc = buf[0];
        #pragma unroll
        for (int v = 1; v < 8; ++v) {
            mn = f4min(mn, buf[v]); mx = f4max(mx, buf[v]); f4add(acc, buf[v]);
        }
        // reduce across the 8 t-offsets (lanes sharing cg are stride-8)
        #pragma unroll
        for (int m = 8; m <= 32; m <<= 1) {
            mn = f4min(mn, shflxor4(mn, m));
            mx = f4max(mx, shflxor4(mx, m));
            f4add(acc, shflxor4(acc, m));
        }
        mnS[u] = mn; mxS[u] = mx;

        if (lane < 8) {               // lane == cg: full-segment raw sum
            const int b = u * 64 + bofs;
            *(float4*)&ws[SUM_OFF + b * (PP * CC) + s * CC + cg * 4] = acc;
        }
    }

    // end-of-kernel cross-wave min/max combine (single barrier, loads done)
    if (lane < 8) {
        #pragma unroll
        for (int u = 0; u < 4; ++u) { cmn[wave][u][cg] = mnS[u]; cmx[wave][u][cg] = mxS[u]; }
    }
    __syncthreads();

    if (wave < 2 && lane < 32) {
        const int u = lane >> 3, c = lane & 7;
        const int b = u * 64 + bofs;
        if (wave == 0) {
            float4 m = f4min(f4min(cmn[0][u][c], cmn[1][u][c]),
                             f4min(cmn[2][u][c], cmn[3][u][c]));
            *(float4*)&ws[MN_OFF + b * (16 * CC) + (blk & 15) * CC + c * 4] = m;
        } else {
            float4 m = f4max(f4max(cmx[0][u][c], cmx[1][u][c]),
                             f4max(cmx[2][u][c], cmx[3][u][c]));
            *(float4*)&ws[MX_OFF + b * (16 * CC) + (blk & 15) * CC + c * 4] = m;
        }
    }
}

// ---------------- K2: outer product + store ----------------
// grid 1024 = B*4, block 256 (4 waves). Block (b, iq): i in [iq*16, iq*16+16).
__global__ __launch_bounds__(256, 4) void gaf_outer(const float* __restrict__ ws,
                                                    float* __restrict__ out) {
    __shared__ float sp[PP * PSTR];
    __shared__ float sy[PP * PSTR];
    __shared__ float4 lmn[32];
    __shared__ float4 lmx[32];

    const int tid  = threadIdx.x;
    const int lane = tid & 63;
    const int wave = tid >> 6;        // 0..3
    const int cg   = lane & 7;
    const int blk  = blockIdx.x;
    const int b    = blk >> 2;
    const int i0   = (blk & 3) * 16;

    // A: reduce the 16 block-level min/max partials
    {
        const int r = (wave & 1) * 8 + (lane >> 3);   // 0..15 (waves 2,3 duplicate)
        float4 mnk = *(const float4*)&ws[MN_OFF + b * (16 * CC) + r * CC + cg * 4];
        float4 mxk = *(const float4*)&ws[MX_OFF + b * (16 * CC) + r * CC + cg * 4];
        #pragma unroll
        for (int m = 8; m <= 32; m <<= 1) {
            mnk = f4min(mnk, shflxor4(mnk, m));
            mxk = f4max(mxk, shflxor4(mxk, m));
        }
        if (lane < 8) { lmn[wave * 8 + cg] = mnk; lmx[wave * 8 + cg] = mxk; }
    }
    __syncthreads();

    // B: finalize min/max (broadcast reads), compute p/y into LDS
    {
        const int cq = tid & 7;
        float4 mnf = f4min(f4min(lmn[cq], lmn[8 + cq]), f4min(lmn[16 + cq], lmn[24 + cq]));
        float4 mxf = f4max(f4max(lmx[cq], lmx[8 + cq]), f4max(lmx[16 + cq], lmx[24 + cq]));
        float4 inv;
        inv.x = 1.0f / (mxf.x - mnf.x);  inv.y = 1.0f / (mxf.y - mnf.y);
        inv.z = 1.0f / (mxf.z - mnf.z);  inv.w = 1.0f / (mxf.w - mnf.w);
        const float s64 = 1.0f / 64.0f;
        #pragma unroll
        for (int h = 0; h < 2; ++h) {
            const int s = (tid >> 3) + h * 32;
            float4 sum = *(const float4*)&ws[SUM_OFF + b * (PP * CC) + s * CC + cq * 4];
            float4 p, y;
            p.x = (sum.x * s64 - mnf.x) * inv.x;  p.y = (sum.y * s64 - mnf.y) * inv.y;
            p.z = (sum.z * s64 - mnf.z) * inv.z;  p.w = (sum.w * s64 - mnf.w) * inv.w;
            y.x = sqrtf(fmaxf(1.f - p.x * p.x, 0.f));  y.y = sqrtf(fmaxf(1.f - p.y * p.y, 0.f));
            y.z = sqrtf(fmaxf(1.f - p.z * p.z, 0.f));  y.w = sqrtf(fmaxf(1.f - p.w * p.w, 0.f));
            *(float4*)&sp[s * PSTR + cq * 4] = p;
            *(float4*)&sy[s * PSTR + cq * 4] = y;
        }
    }
    __syncthreads();

    // D: out[b,i,j,c] = y_i*p_j - p_i*y_j ; wave w owns i in [i0+4w, i0+4w+4)
    const int jrow = lane >> 3;
    float4 pj[8], yj[8];
    #pragma unroll
    for (int jc = 0; jc < 8; ++jc) {
        const int j = jc * 8 + jrow;
        pj[jc] = *(const float4*)&sp[j * PSTR + cg * 4];
        yj[jc] = *(const float4*)&sy[j * PSTR + cg * 4];
    }

    float4* ob = (float4*)out + (size_t)b * (PP * PP * CC / 4) + lane;

    #pragma unroll
    for (int ii = 0; ii < 4; ++ii) {
        const int i = i0 + wave * 4 + ii;
        const float4 pi = *(const float4*)&sp[i * PSTR + cg * 4];
        const float4 yi = *(const float4*)&sy[i * PSTR + cg * 4];
        #pragma unroll
        for (int jc = 0; jc < 8; ++jc) {
            float4 r;
            r.x = yi.x * pj[jc].x - pi.x * yj[jc].x;
            r.y = yi.y * pj[jc].y - pi.y * yj[jc].y;
            r.z = yi.z * pj[jc].z - pi.z * yj[jc].z;
            r.w = yi.w * pj[jc].w - pi.w * yj[jc].w;
            ob[i * 512 + jc * 64] = r;
        }
    }
}

// ---------------- fallback: fused kernel (used if ws too small) ----------------
__global__ __launch_bounds__(1024, 4) void gaf_fused(const float* __restrict__ x,
                                                     float* __restrict__ out) {
    __shared__ float sp[PP * PSTR];
    __shared__ float sy[PP * PSTR];
    __shared__ float redmin[16 * CC];
    __shared__ float redmax[16 * CC];

    const int tid  = threadIdx.x;
    const int lane = tid & 63;
    const int wave = tid >> 6;
    const int cg   = lane & 7;
    const int b    = blockIdx.x;

    const float4* xw = (const float4*)x + (size_t)b * (TT * CC / 4) + wave * 2048 + lane;

    const float FBIG = 3.402823466e+38f;
    float4 mn = make_float4(FBIG, FBIG, FBIG, FBIG);
    float4 mx = make_float4(-FBIG, -FBIG, -FBIG, -FBIG);
    float4 acc[4];
    #pragma unroll
    for (int g = 0; g < 4; ++g) acc[g] = make_float4(0.f, 0.f, 0.f, 0.f);

    #pragma unroll
    for (int g = 0; g < 4; ++g) {
        float4 buf[8];
        #pragma unroll
        for (int u = 0; u < 8; ++u) buf[u] = xw[(g * 8 + u) * 64];
        #pragma unroll
        for (int u = 0; u < 8; ++u) {
            mn = f4min(mn, buf[u]); mx = f4max(mx, buf[u]); f4add(acc[g], buf[u]);
        }
    }

    #pragma unroll
    for (int m = 8; m <= 32; m <<= 1) {
        mn = f4min(mn, shflxor4(mn, m));
        mx = f4max(mx, shflxor4(mx, m));
        #pragma unroll
        for (int g = 0; g < 4; ++g) f4add(acc[g], shflxor4(acc[g], m));
    }

    if (lane < 8) {
        *(float4*)&redmin[wave * CC + cg * 4] = mn;
        *(float4*)&redmax[wave * CC + cg * 4] = mx;
    }
    __syncthreads();

    float4 gmn = *(const float4*)&redmin[0 * CC + cg * 4];
    float4 gmx = *(const float4*)&redmax[0 * CC + cg * 4];
    #pragma unroll
    for (int w = 1; w < 16; ++w) {
        gmn = f4min(gmn, *(const float4*)&redmin[w * CC + cg * 4]);
        gmx = f4max(gmx, *(const float4*)&redmax[w * CC + cg * 4]);
    }

    float4 inv;
    inv.x = 1.0f / (gmx.x - gmn.x);  inv.y = 1.0f / (gmx.y - gmn.y);
    inv.z = 1.0f / (gmx.z - gmn.z);  inv.w = 1.0f / (gmx.w - gmn.w);
    const float s64 = 1.0f / 64.0f;

    if (lane < 8) {
        #pragma unroll
        for (int g = 0; g < 4; ++g) {
            float4 p, y;
            p.x = (acc[g].x * s64 - gmn.x) * inv.x;  p.y = (acc[g].y * s64 - gmn.y) * inv.y;
            p.z = (acc[g].z * s64 - gmn.z) * inv.z;  p.w = (acc[g].w * s64 - gmn.w) * inv.w;
            y.x = sqrtf(fmaxf(1.f - p.x * p.x, 0.f));  y.y = sqrtf(fmaxf(1.f - p.y * p.y, 0.f));
            y.z = sqrtf(fmaxf(1.f - p.z * p.z, 0.f));  y.w = sqrtf(fmaxf(1.f - p.w * p.w, 0.f));
            const int s = wave * 4 + g;
            *(float4*)&sp[s * PSTR + cg * 4] = p;
            *(float4*)&sy[s * PSTR + cg * 4] = y;
        }
    }
    __syncthreads();

    const int jrow = lane >> 3;
    float4 pj[8], yj[8];
    #pragma unroll
    for (int jc = 0; jc < 8; ++jc) {
        const int j = jc * 8 + jrow;
        pj[jc] = *(const float4*)&sp[j * PSTR + cg * 4];
        yj[jc] = *(const float4*)&sy[j * PSTR + cg * 4];
    }

    float4* ob = (float4*)out + (size_t)b * (PP * PP * CC / 4) + wave * 2048 + lane;

    #pragma unroll
    for (int ii = 0; ii < 4; ++ii) {
        const float4 pi = *(const float4*)&sp[(wave * 4 + ii) * PSTR + cg * 4];
        const float4 yi = *(const float4*)&sy[(wave * 4 + ii) * PSTR + cg * 4];
        #pragma unroll
        for (int jc = 0; jc < 8; ++jc) {
            float4 r;
            r.x = yi.x * pj[jc].x - pi.x * yj[jc].x;
            r.y = yi.y * pj[jc].y - pi.y * yj[jc].y;
            r.z = yi.z * pj[jc].z - pi.z * yj[jc].z;
            r.w = yi.w * pj[jc].w - pi.w * yj[jc].w;
            ob[ii * 512 + jc * 64] = r;
        }
    }
}

extern "C" void kernel_launch(void* const* d_in, const int* in_sizes, int n_in,
                              void* d_out, int out_size, void* d_ws, size_t ws_size,
                              hipStream_t stream) {
    const float* x = (const float*)d_in[0];
    float* out = (float*)d_out;
    if (d_ws != nullptr && ws_size >= (size_t)WS_BYTES) {
        float* ws = (float*)d_ws;
        // EXPERIMENT: K1 launched twice (idempotent). dur_us = C + 2*K1 + K2
        // reveals K1's absolute duration; see header comment for readout table.
        gaf_stats<<<1024, 256, 0, stream>>>(x, ws);
        gaf_stats<<<1024, 256, 0, stream>>>(x, ws);
        gaf_outer<<<BB * 4, 256, 0, stream>>>(ws, out);
    } else {
        gaf_fused<<<BB, 1024, 0, stream>>>(x, out);
    }
}

// Round 5
// 221.548 us; speedup vs baseline: 1.0981x; 1.0981x over previous
//
#include <hip/hip_runtime.h>
#include <math.h>

// x [B=256, T=4096, C=32] f32 -> out [B, 64, 64, 32] f32, PAA=64, GADF.
//
// R7: single-launch NT split. Identical kernels to R6; the only change is
// removing the duplicate K1 launch (R6 ran K1 twice to expose K1's absolute
// time via dur differencing).
//   Algebra: C=148.8 fixed overhead; R6 dur 243.3 = C + 2*K1nt + K2.
//   => This round: K1nt = 243.3 - dur ; K2 = dur - 148.8 - K1nt.
// NT loads are KEPT: R5->R6 differencing proved 2*K1nt - K1 = 7.0, i.e. NT
// roughly halved K1 (L2 read-allocate thrash: 134 MB streaming through 32 MB
// L2; nt bypasses allocation).
// K2 unchanged (plain stores) to keep the algebra clean.

#define BB   256
#define TT   4096
#define CC   32
#define PP   64
#define PSTR 33

typedef float f32x4 __attribute__((ext_vector_type(4)));

// ws layout (floats)
#define SUM_OFF    0                        // [b][64][32] raw segment sums (2 MB)
#define SUM_FLOATS (BB * PP * CC)           // 524288
#define MN_OFF     SUM_FLOATS               // [b][16][32] block-level mins (512 KB)
#define MM_FLOATS  (BB * 16 * CC)           // 131072
#define MX_OFF     (MN_OFF + MM_FLOATS)     // [b][16][32] block-level maxs
#define WS_FLOATS  (MX_OFF + MM_FLOATS)     // 786432 floats = 3 MB
#define WS_BYTES   (WS_FLOATS * 4)

__device__ __forceinline__ float4 f4min(float4 a, float4 b) {
    return make_float4(fminf(a.x,b.x), fminf(a.y,b.y), fminf(a.z,b.z), fminf(a.w,b.w));
}
__device__ __forceinline__ float4 f4max(float4 a, float4 b) {
    return make_float4(fmaxf(a.x,b.x), fmaxf(a.y,b.y), fmaxf(a.z,b.z), fmaxf(a.w,b.w));
}
__device__ __forceinline__ void f4add(float4& a, float4 v) {
    a.x += v.x; a.y += v.y; a.z += v.z; a.w += v.w;
}
__device__ __forceinline__ float4 shflxor4(float4 v, int m) {
    return make_float4(__shfl_xor(v.x, m), __shfl_xor(v.y, m),
                       __shfl_xor(v.z, m), __shfl_xor(v.w, m));
}
__device__ __forceinline__ float4 ntload4(const float4* src) {
    f32x4 t = __builtin_nontemporal_load((const f32x4*)src);
    return make_float4(t.x, t.y, t.z, t.w);
}

// ---------------- K1: dense-window streaming stats (NT loads) ----------------
// Wave W = blk*4+wave. Step u: f4 addr = u*2M + W*512 + v*64 + lane, v=0..7.
// Decode: b = u*64 + (W>>6); s = W&63 (full segment owned in-wave).
__global__ __launch_bounds__(256, 4) void gaf_stats(const float* __restrict__ x,
                                                    float* __restrict__ ws) {
    __shared__ float4 cmn[4][4][8];   // [wave][step][cg]
    __shared__ float4 cmx[4][4][8];

    const int tid  = threadIdx.x;
    const int lane = tid & 63;
    const int wave = tid >> 6;        // 0..3
    const int cg   = lane & 7;
    const int blk  = blockIdx.x;
    const int W    = blk * 4 + wave;  // 0..4095
    const int s    = W & 63;          // segment owned by this wave
    const int bofs = W >> 6;          // b = u*64 + bofs (uniform across block)

    const float4* xb = (const float4*)x + (size_t)W * 512 + lane;

    float4 mnS[4], mxS[4];

    #pragma unroll
    for (int u = 0; u < 4; ++u) {
        const float4* g = xb + (size_t)u * 2097152;   // 32 MB window step
        float4 buf[8];
        #pragma unroll
        for (int v = 0; v < 8; ++v) buf[v] = ntload4(&g[v * 64]);

        float4 mn = buf[0], mx = buf[0], acc = buf[0];
        #pragma unroll
        for (int v = 1; v < 8; ++v) {
            mn = f4min(mn, buf[v]); mx = f4max(mx, buf[v]); f4add(acc, buf[v]);
        }
        // reduce across the 8 t-offsets (lanes sharing cg are stride-8)
        #pragma unroll
        for (int m = 8; m <= 32; m <<= 1) {
            mn = f4min(mn, shflxor4(mn, m));
            mx = f4max(mx, shflxor4(mx, m));
            f4add(acc, shflxor4(acc, m));
        }
        mnS[u] = mn; mxS[u] = mx;

        if (lane < 8) {               // lane == cg: full-segment raw sum
            const int b = u * 64 + bofs;
            *(float4*)&ws[SUM_OFF + b * (PP * CC) + s * CC + cg * 4] = acc;
        }
    }

    // end-of-kernel cross-wave min/max combine (single barrier, loads done)
    if (lane < 8) {
        #pragma unroll
        for (int u = 0; u < 4; ++u) { cmn[wave][u][cg] = mnS[u]; cmx[wave][u][cg] = mxS[u]; }
    }
    __syncthreads();

    if (wave < 2 && lane < 32) {
        const int u = lane >> 3, c = lane & 7;
        const int b = u * 64 + bofs;
        if (wave == 0) {
            float4 m = f4min(f4min(cmn[0][u][c], cmn[1][u][c]),
                             f4min(cmn[2][u][c], cmn[3][u][c]));
            *(float4*)&ws[MN_OFF + b * (16 * CC) + (blk & 15) * CC + c * 4] = m;
        } else {
            float4 m = f4max(f4max(cmx[0][u][c], cmx[1][u][c]),
                             f4max(cmx[2][u][c], cmx[3][u][c]));
            *(float4*)&ws[MX_OFF + b * (16 * CC) + (blk & 15) * CC + c * 4] = m;
        }
    }
}

// ---------------- K2: outer product + store ----------------
// grid 1024 = B*4, block 256 (4 waves). Block (b, iq): i in [iq*16, iq*16+16).
__global__ __launch_bounds__(256, 4) void gaf_outer(const float* __restrict__ ws,
                                                    float* __restrict__ out) {
    __shared__ float sp[PP * PSTR];
    __shared__ float sy[PP * PSTR];
    __shared__ float4 lmn[32];
    __shared__ float4 lmx[32];

    const int tid  = threadIdx.x;
    const int lane = tid & 63;
    const int wave = tid >> 6;        // 0..3
    const int cg   = lane & 7;
    const int blk  = blockIdx.x;
    const int b    = blk >> 2;
    const int i0   = (blk & 3) * 16;

    // A: reduce the 16 block-level min/max partials
    {
        const int r = (wave & 1) * 8 + (lane >> 3);   // 0..15 (waves 2,3 duplicate)
        float4 mnk = *(const float4*)&ws[MN_OFF + b * (16 * CC) + r * CC + cg * 4];
        float4 mxk = *(const float4*)&ws[MX_OFF + b * (16 * CC) + r * CC + cg * 4];
        #pragma unroll
        for (int m = 8; m <= 32; m <<= 1) {
            mnk = f4min(mnk, shflxor4(mnk, m));
            mxk = f4max(mxk, shflxor4(mxk, m));
        }
        if (lane < 8) { lmn[wave * 8 + cg] = mnk; lmx[wave * 8 + cg] = mxk; }
    }
    __syncthreads();

    // B: finalize min/max (broadcast reads), compute p/y into LDS
    {
        const int cq = tid & 7;
        float4 mnf = f4min(f4min(lmn[cq], lmn[8 + cq]), f4min(lmn[16 + cq], lmn[24 + cq]));
        float4 mxf = f4max(f4max(lmx[cq], lmx[8 + cq]), f4max(lmx[16 + cq], lmx[24 + cq]));
        float4 inv;
        inv.x = 1.0f / (mxf.x - mnf.x);  inv.y = 1.0f / (mxf.y - mnf.y);
        inv.z = 1.0f / (mxf.z - mnf.z);  inv.w = 1.0f / (mxf.w - mnf.w);
        const float s64 = 1.0f / 64.0f;
        #pragma unroll
        for (int h = 0; h < 2; ++h) {
            const int s = (tid >> 3) + h * 32;
            float4 sum = *(const float4*)&ws[SUM_OFF + b * (PP * CC) + s * CC + cq * 4];
            float4 p, y;
            p.x = (sum.x * s64 - mnf.x) * inv.x;  p.y = (sum.y * s64 - mnf.y) * inv.y;
            p.z = (sum.z * s64 - mnf.z) * inv.z;  p.w = (sum.w * s64 - mnf.w) * inv.w;
            y.x = sqrtf(fmaxf(1.f - p.x * p.x, 0.f));  y.y = sqrtf(fmaxf(1.f - p.y * p.y, 0.f));
            y.z = sqrtf(fmaxf(1.f - p.z * p.z, 0.f));  y.w = sqrtf(fmaxf(1.f - p.w * p.w, 0.f));
            *(float4*)&sp[s * PSTR + cq * 4] = p;
            *(float4*)&sy[s * PSTR + cq * 4] = y;
        }
    }
    __syncthreads();

    // D: out[b,i,j,c] = y_i*p_j - p_i*y_j ; wave w owns i in [i0+4w, i0+4w+4)
    const int jrow = lane >> 3;
    float4 pj[8], yj[8];
    #pragma unroll
    for (int jc = 0; jc < 8; ++jc) {
        const int j = jc * 8 + jrow;
        pj[jc] = *(const float4*)&sp[j * PSTR + cg * 4];
        yj[jc] = *(const float4*)&sy[j * PSTR + cg * 4];
    }

    float4* ob = (float4*)out + (size_t)b * (PP * PP * CC / 4) + lane;

    #pragma unroll
    for (int ii = 0; ii < 4; ++ii) {
        const int i = i0 + wave * 4 + ii;
        const float4 pi = *(const float4*)&sp[i * PSTR + cg * 4];
        const float4 yi = *(const float4*)&sy[i * PSTR + cg * 4];
        #pragma unroll
        for (int jc = 0; jc < 8; ++jc) {
            float4 r;
            r.x = yi.x * pj[jc].x - pi.x * yj[jc].x;
            r.y = yi.y * pj[jc].y - pi.y * yj[jc].y;
            r.z = yi.z * pj[jc].z - pi.z * yj[jc].z;
            r.w = yi.w * pj[jc].w - pi.w * yj[jc].w;
            ob[i * 512 + jc * 64] = r;
        }
    }
}

// ---------------- fallback: fused kernel (used if ws too small) ----------------
__global__ __launch_bounds__(1024, 4) void gaf_fused(const float* __restrict__ x,
                                                     float* __restrict__ out) {
    __shared__ float sp[PP * PSTR];
    __shared__ float sy[PP * PSTR];
    __shared__ float redmin[16 * CC];
    __shared__ float redmax[16 * CC];

    const int tid  = threadIdx.x;
    const int lane = tid & 63;
    const int wave = tid >> 6;
    const int cg   = lane & 7;
    const int b    = blockIdx.x;

    const float4* xw = (const float4*)x + (size_t)b * (TT * CC / 4) + wave * 2048 + lane;

    const float FBIG = 3.402823466e+38f;
    float4 mn = make_float4(FBIG, FBIG, FBIG, FBIG);
    float4 mx = make_float4(-FBIG, -FBIG, -FBIG, -FBIG);
    float4 acc[4];
    #pragma unroll
    for (int g = 0; g < 4; ++g) acc[g] = make_float4(0.f, 0.f, 0.f, 0.f);

    #pragma unroll
    for (int g = 0; g < 4; ++g) {
        float4 buf[8];
        #pragma unroll
        for (int u = 0; u < 8; ++u) buf[u] = xw[(g * 8 + u) * 64];
        #pragma unroll
        for (int u = 0; u < 8; ++u) {
            mn = f4min(mn, buf[u]); mx = f4max(mx, buf[u]); f4add(acc[g], buf[u]);
        }
    }

    #pragma unroll
    for (int m = 8; m <= 32; m <<= 1) {
        mn = f4min(mn, shflxor4(mn, m));
        mx = f4max(mx, shflxor4(mx, m));
        #pragma unroll
        for (int g = 0; g < 4; ++g) f4add(acc[g], shflxor4(acc[g], m));
    }

    if (lane < 8) {
        *(float4*)&redmin[wave * CC + cg * 4] = mn;
        *(float4*)&redmax[wave * CC + cg * 4] = mx;
    }
    __syncthreads();

    float4 gmn = *(const float4*)&redmin[0 * CC + cg * 4];
    float4 gmx = *(const float4*)&redmax[0 * CC + cg * 4];
    #pragma unroll
    for (int w = 1; w < 16; ++w) {
        gmn = f4min(gmn, *(const float4*)&redmin[w * CC + cg * 4]);
        gmx = f4max(gmx, *(const float4*)&redmax[w * CC + cg * 4]);
    }

    float4 inv;
    inv.x = 1.0f / (gmx.x - gmn.x);  inv.y = 1.0f / (gmx.y - gmn.y);
    inv.z = 1.0f / (gmx.z - gmn.z);  inv.w = 1.0f / (gmx.w - gmn.w);
    const float s64 = 1.0f / 64.0f;

    if (lane < 8) {
        #pragma unroll
        for (int g = 0; g < 4; ++g) {
            float4 p, y;
            p.x = (acc[g].x * s64 - gmn.x) * inv.x;  p.y = (acc[g].y * s64 - gmn.y) * inv.y;
            p.z = (acc[g].z * s64 - gmn.z) * inv.z;  p.w = (acc[g].w * s64 - gmn.w) * inv.w;
            y.x = sqrtf(fmaxf(1.f - p.x * p.x, 0.f));  y.y = sqrtf(fmaxf(1.f - p.y * p.y, 0.f));
            y.z = sqrtf(fmaxf(1.f - p.z * p.z, 0.f));  y.w = sqrtf(fmaxf(1.f - p.w * p.w, 0.f));
            const int s = wave * 4 + g;
            *(float4*)&sp[s * PSTR + cg * 4] = p;
            *(float4*)&sy[s * PSTR + cg * 4] = y;
        }
    }
    __syncthreads();

    const int jrow = lane >> 3;
    float4 pj[8], yj[8];
    #pragma unroll
    for (int jc = 0; jc < 8; ++jc) {
        const int j = jc * 8 + jrow;
        pj[jc] = *(const float4*)&sp[j * PSTR + cg * 4];
        yj[jc] = *(const float4*)&sy[j * PSTR + cg * 4];
    }

    float4* ob = (float4*)out + (size_t)b * (PP * PP * CC / 4) + wave * 2048 + lane;

    #pragma unroll
    for (int ii = 0; ii < 4; ++ii) {
        const float4 pi = *(const float4*)&sp[(wave * 4 + ii) * PSTR + cg * 4];
        const float4 yi = *(const float4*)&sy[(wave * 4 + ii) * PSTR + cg * 4];
        #pragma unroll
        for (int jc = 0; jc < 8; ++jc) {
            float4 r;
            r.x = yi.x * pj[jc].x - pi.x * yj[jc].x;
            r.y = yi.y * pj[jc].y - pi.y * yj[jc].y;
            r.z = yi.z * pj[jc].z - pi.z * yj[jc].z;
            r.w = yi.w * pj[jc].w - pi.w * yj[jc].w;
            ob[ii * 512 + jc * 64] = r;
        }
    }
}

extern "C" void kernel_launch(void* const* d_in, const int* in_sizes, int n_in,
                              void* d_out, int out_size, void* d_ws, size_t ws_size,
                              hipStream_t stream) {
    const float* x = (const float*)d_in[0];
    float* out = (float*)d_out;
    if (d_ws != nullptr && ws_size >= (size_t)WS_BYTES) {
        float* ws = (float*)d_ws;
        gaf_stats<<<1024, 256, 0, stream>>>(x, ws);
        gaf_outer<<<BB * 4, 256, 0, stream>>>(ws, out);
    } else {
        gaf_fused<<<BB, 1024, 0, stream>>>(x, out);
    }
}